// Round 1
// baseline (859.695 us; speedup 1.0000x reference)
//
#include <hip/hip_runtime.h>
#include <cstdint>
#include <cmath>

typedef __attribute__((ext_vector_type(8))) short short8;
typedef __attribute__((ext_vector_type(4))) float floatx4;

#define DEV static __device__ __forceinline__

DEV float bf2f(uint16_t u) {
    union { uint32_t i; float f; } v; v.i = ((uint32_t)u) << 16; return v.f;
}
DEV uint16_t f2bf(float f) {
    union { float f; uint32_t i; } v; v.f = f;
    uint32_t r = (v.i + 0x7FFFu + ((v.i >> 16) & 1u)) >> 16;
    return (uint16_t)r;
}
DEV float swishf(float x) { return x / (1.f + __expf(-x)); }
DEV float geluf(float x) {
    const float c = 0.7978845608028654f;
    float t = tanhf(c * (x + 0.044715f * x * x * x));
    return 0.5f * x * (1.f + t);
}

// ---------------- convert fp32 -> bf16 (flat) ----------------
__global__ __launch_bounds__(256) void cvt_k(const float* __restrict__ src,
                                             uint16_t* __restrict__ dst, int n4) {
    int i = blockIdx.x * 256 + threadIdx.x;
    if (i >= n4) return;
    float4 f = ((const float4*)src)[i];
    uint16_t tmp[4] = { f2bf(f.x), f2bf(f.y), f2bf(f.z), f2bf(f.w) };
    ((uint2*)dst)[i] = *(uint2*)tmp;
}

// ---------------- batched transpose+convert: W[K,N=256] -> Wt[N][K] bf16 ----------------
struct TArg { const float* src[15]; };

__global__ __launch_bounds__(256) void tpose_k(TArg ta, uint16_t* __restrict__ arena) {
    int z = blockIdx.z;
    const float* src; uint16_t* dst; int K;
    if (z == 0) {
        if (blockIdx.y) return;
        src = ta.src[0]; dst = arena; K = 32;                 // w_enc [32,256]
    } else if (z <= 39) {
        int q = z - 1; int ti = q / 3, s = q % 3;
        src = ta.src[1 + ti] + (size_t)s * 65536;
        dst = arena + 8192 + (size_t)(ti * 3 + s) * 65536; K = 256;
    } else {
        src = ta.src[14]; dst = arena + 2564096; K = 256;     // hw1
    }
    int k0 = blockIdx.y << 5;   // K tile (32)
    int n0 = blockIdx.x << 6;   // N tile (64), N = 256
    __shared__ __align__(16) uint16_t tile[32][72];
    int t = threadIdx.x;
    {
        int r = t >> 3, c = (t & 7) << 3;
        const float* s0 = src + (size_t)(k0 + r) * 256 + n0 + c;
        float4 f0 = *(const float4*)s0;
        float4 f1 = *(const float4*)(s0 + 4);
        tile[r][c + 0] = f2bf(f0.x); tile[r][c + 1] = f2bf(f0.y);
        tile[r][c + 2] = f2bf(f0.z); tile[r][c + 3] = f2bf(f0.w);
        tile[r][c + 4] = f2bf(f1.x); tile[r][c + 5] = f2bf(f1.y);
        tile[r][c + 6] = f2bf(f1.z); tile[r][c + 7] = f2bf(f1.w);
    }
    __syncthreads();
    {
        int n = t >> 2, c = (t & 3) << 3;
        uint16_t tmp[8];
#pragma unroll
        for (int j = 0; j < 8; ++j) tmp[j] = tile[c + j][n];
        *(uint4*)&dst[(size_t)(n0 + n) * K + k0 + c] = *(uint4*)tmp;
    }
}

// ---------------- GEMM: A[M=16384,K] bf16 @ Wt[N=256][K] bf16, fused epilogues ----------------
enum { EP_NONE = 0, EP_GELU_RMS = 1, EP_RESID_RMS = 2, EP_MUL = 3 };

template<int EPI>
__global__ __launch_bounds__(256) void gemm_k(
    const uint16_t* __restrict__ A, const uint16_t* __restrict__ Wt, int K,
    const float* __restrict__ bias, const float* __restrict__ resid,
    const uint16_t* __restrict__ mulg, const float* __restrict__ lnw,
    float* __restrict__ xout, uint16_t* __restrict__ bout)
{
    __shared__ __align__(16) uint16_t As[32][40];
    __shared__ __align__(16) uint16_t Bs[256][40];
    __shared__ float rowsum[4][32];
    const int t = threadIdx.x;
    const int w = t >> 6, lane = t & 63, l16 = lane & 15, lg = lane >> 4;
    const int m0 = blockIdx.x * 32;

    floatx4 acc[2][4];
#pragma unroll
    for (int i = 0; i < 2; ++i)
#pragma unroll
        for (int j = 0; j < 4; ++j) acc[i][j] = (floatx4){0.f, 0.f, 0.f, 0.f};

    const int nk = K >> 5;
    for (int kc = 0; kc < nk; ++kc) {
        const int k0 = kc << 5;
        if (t < 128) {
            int r = t >> 2, c = (t & 3) << 3;
            *(uint4*)&As[r][c] = *(const uint4*)(A + (size_t)(m0 + r) * K + k0 + c);
        }
        {
            const uint16_t* wr = Wt + (size_t)t * K + k0;
            *(uint4*)&Bs[t][0]  = ((const uint4*)wr)[0];
            *(uint4*)&Bs[t][8]  = ((const uint4*)wr)[1];
            *(uint4*)&Bs[t][16] = ((const uint4*)wr)[2];
            *(uint4*)&Bs[t][24] = ((const uint4*)wr)[3];
        }
        __syncthreads();
        short8 aF[2], bF[4];
#pragma unroll
        for (int rt = 0; rt < 2; ++rt)
            aF[rt] = *(const short8*)&As[(rt << 4) + l16][lg << 3];
#pragma unroll
        for (int ct = 0; ct < 4; ++ct)
            bF[ct] = *(const short8*)&Bs[(w << 6) + (ct << 4) + l16][lg << 3];
#pragma unroll
        for (int rt = 0; rt < 2; ++rt)
#pragma unroll
            for (int ct = 0; ct < 4; ++ct)
                acc[rt][ct] = __builtin_amdgcn_mfma_f32_16x16x32_bf16(
                    aF[rt], bF[ct], acc[rt][ct], 0, 0, 0);
        __syncthreads();
    }

    // epilogue: transform
    float v[2][4][4];
#pragma unroll
    for (int rt = 0; rt < 2; ++rt)
#pragma unroll
        for (int ct = 0; ct < 4; ++ct)
#pragma unroll
            for (int r = 0; r < 4; ++r) {
                int row = (rt << 4) + (lg << 2) + r;
                int col = (w << 6) + (ct << 4) + l16;
                size_t idx = (size_t)(m0 + row) * 256 + col;
                float x = acc[rt][ct][r];
                if (EPI == EP_GELU_RMS) { if (bias) x += bias[col]; x = geluf(x); }
                if (EPI == EP_RESID_RMS) x += resid[idx];
                if (EPI == EP_MUL) x *= swishf(bf2f(mulg[idx]));
                v[rt][ct][r] = x;
            }

    if (EPI == EP_GELU_RMS || EPI == EP_RESID_RMS) {
#pragma unroll
        for (int rt = 0; rt < 2; ++rt)
#pragma unroll
            for (int r = 0; r < 4; ++r) {
                float p = 0.f;
#pragma unroll
                for (int ct = 0; ct < 4; ++ct) p += v[rt][ct][r] * v[rt][ct][r];
                p += __shfl_xor(p, 1, 64); p += __shfl_xor(p, 2, 64);
                p += __shfl_xor(p, 4, 64); p += __shfl_xor(p, 8, 64);
                int row = (rt << 4) + (lg << 2) + r;
                if (l16 == 0) rowsum[w][row] = p;
            }
        __syncthreads();
#pragma unroll
        for (int rt = 0; rt < 2; ++rt)
#pragma unroll
            for (int r = 0; r < 4; ++r) {
                int row = (rt << 4) + (lg << 2) + r;
                float tot = rowsum[0][row] + rowsum[1][row] + rowsum[2][row] + rowsum[3][row];
                float rn = rsqrtf(tot * (1.f / 256.f) + 1e-6f);
#pragma unroll
                for (int ct = 0; ct < 4; ++ct) {
                    int col = (w << 6) + (ct << 4) + l16;
                    size_t idx = (size_t)(m0 + row) * 256 + col;
                    float o = v[rt][ct][r] * rn * lnw[col];
                    bout[idx] = f2bf(o);
                    if (xout) xout[idx] = o;
                }
            }
    } else {
#pragma unroll
        for (int rt = 0; rt < 2; ++rt)
#pragma unroll
            for (int ct = 0; ct < 4; ++ct)
#pragma unroll
                for (int r = 0; r < 4; ++r) {
                    int row = (rt << 4) + (lg << 2) + r;
                    int col = (w << 6) + (ct << 4) + l16;
                    size_t idx = (size_t)(m0 + row) * 256 + col;
                    bout[idx] = f2bf(v[rt][ct][r]);
                }
    }
}

// ---------------- retention attention, fused groupnorm + swish gate ----------------
struct GArg { float l2g[8]; };

__global__ __launch_bounds__(256) void attn_k(
    const uint16_t* __restrict__ q, const uint16_t* __restrict__ kbuf,
    const uint16_t* __restrict__ vbuf, const uint16_t* __restrict__ g,
    const float* __restrict__ gns, const float* __restrict__ gnb,
    uint16_t* __restrict__ out, GArg ga)
{
    __shared__ __align__(16) uint16_t QS[256][40];   // Q, then per-wave S-tile region
    __shared__ __align__(16) uint16_t Ks[256][40];
    __shared__ __align__(16) uint16_t Vt[32][264];
    const int b = blockIdx.x >> 3, h = blockIdx.x & 7;
    const float l2g = ga.l2g[h];
    const int t = threadIdx.x, w = t >> 6, lane = t & 63, l16 = lane & 15, lg = lane >> 4;
    const size_t base = ((size_t)b * 256) * 256 + (size_t)h * 32;

    {   // stage: Q,K rows; V transposed
        const uint4* qr = (const uint4*)(q + base + (size_t)t * 256);
        *(uint4*)&QS[t][0] = qr[0]; *(uint4*)&QS[t][8] = qr[1];
        *(uint4*)&QS[t][16] = qr[2]; *(uint4*)&QS[t][24] = qr[3];
        const uint4* kr = (const uint4*)(kbuf + base + (size_t)t * 256);
        *(uint4*)&Ks[t][0] = kr[0]; *(uint4*)&Ks[t][8] = kr[1];
        *(uint4*)&Ks[t][16] = kr[2]; *(uint4*)&Ks[t][24] = kr[3];
        union { uint4 v4[4]; uint16_t u[32]; } vv;
        const uint4* vr = (const uint4*)(vbuf + base + (size_t)t * 256);
        vv.v4[0] = vr[0]; vv.v4[1] = vr[1]; vv.v4[2] = vr[2]; vv.v4[3] = vr[3];
#pragma unroll
        for (int d = 0; d < 32; ++d) Vt[d][t] = vv.u[d];
    }
    __syncthreads();

    short8 qF[4];
#pragma unroll
    for (int rt = 0; rt < 4; ++rt)
        qF[rt] = *(const short8*)&QS[(w << 6) + (rt << 4) + l16][lg << 3];
    __syncthreads();

    floatx4 racc[4][2];
#pragma unroll
    for (int i = 0; i < 4; ++i) { racc[i][0] = (floatx4){0,0,0,0}; racc[i][1] = (floatx4){0,0,0,0}; }

    const float invsq = 0.17677669529663687f;  // 1/sqrt(32)
    for (int jt = 0; jt < 8; ++jt) {
        const int j0 = jt << 5;
        floatx4 sacc[4][2];
#pragma unroll
        for (int i = 0; i < 4; ++i) { sacc[i][0] = (floatx4){0,0,0,0}; sacc[i][1] = (floatx4){0,0,0,0}; }
        short8 kF[2];
#pragma unroll
        for (int ct = 0; ct < 2; ++ct)
            kF[ct] = *(const short8*)&Ks[j0 + (ct << 4) + l16][lg << 3];
#pragma unroll
        for (int rt = 0; rt < 4; ++rt)
#pragma unroll
            for (int ct = 0; ct < 2; ++ct)
                sacc[rt][ct] = __builtin_amdgcn_mfma_f32_16x16x32_bf16(
                    qF[rt], kF[ct], sacc[rt][ct], 0, 0, 0);
        // decay + causal mask, write S (bf16) into this wave's QS region
#pragma unroll
        for (int rt = 0; rt < 4; ++rt)
#pragma unroll
            for (int ct = 0; ct < 2; ++ct)
#pragma unroll
                for (int r = 0; r < 4; ++r) {
                    int row = (rt << 4) + (lg << 2) + r;     // 0..63
                    int i = (w << 6) + row;
                    int j = j0 + (ct << 4) + l16;
                    float sv = 0.f;
                    if (i >= j)
                        sv = sacc[rt][ct][r] * invsq *
                             exp2f((float)((i >> 3) - (j >> 3)) * l2g);
                    QS[(w << 6) + row][(ct << 4) + l16] = f2bf(sv);
                }
        __syncthreads();
        // PV
        short8 vF[2];
#pragma unroll
        for (int ct = 0; ct < 2; ++ct)
            vF[ct] = *(const short8*)&Vt[(ct << 4) + l16][j0 + (lg << 3)];
#pragma unroll
        for (int rt = 0; rt < 4; ++rt) {
            short8 sF = *(const short8*)&QS[(w << 6) + (rt << 4) + l16][lg << 3];
#pragma unroll
            for (int ct = 0; ct < 2; ++ct)
                racc[rt][ct] = __builtin_amdgcn_mfma_f32_16x16x32_bf16(
                    sF, vF[ct], racc[rt][ct], 0, 0, 0);
        }
        __syncthreads();
    }

    // groupnorm (per row over this head's 32 features) + swish gate
#pragma unroll
    for (int rt = 0; rt < 4; ++rt)
#pragma unroll
        for (int r = 0; r < 4; ++r) {
            float v0 = racc[rt][0][r], v1 = racc[rt][1][r];
            float s1 = v0 + v1, s2 = v0 * v0 + v1 * v1;
            s1 += __shfl_xor(s1, 1, 64); s2 += __shfl_xor(s2, 1, 64);
            s1 += __shfl_xor(s1, 2, 64); s2 += __shfl_xor(s2, 2, 64);
            s1 += __shfl_xor(s1, 4, 64); s2 += __shfl_xor(s2, 4, 64);
            s1 += __shfl_xor(s1, 8, 64); s2 += __shfl_xor(s2, 8, 64);
            float mu = s1 * (1.f / 32.f);
            float var = s2 * (1.f / 32.f) - mu * mu;
            float rstd = rsqrtf(var + 1e-5f);
            int srow = (w << 6) + (rt << 4) + (lg << 2) + r;
            size_t obase = ((size_t)b * 256 + srow) * 256 + (size_t)h * 32;
#pragma unroll
            for (int ct = 0; ct < 2; ++ct) {
                int d = (ct << 4) + l16;
                float x = ct ? v1 : v0;
                float y = (x - mu) * rstd * gns[h * 32 + d] + gnb[h * 32 + d];
                float gv = swishf(bf2f(g[obase + d]));
                out[obase + d] = f2bf(y * gv);
            }
        }
}

// ---------------- final head: out = h @ hw2 + hb2  (N=32, fp32 out) ----------------
__global__ __launch_bounds__(256) void head_out_k(
    const uint16_t* __restrict__ h, const float* __restrict__ w2,
    const float* __restrict__ b2, float* __restrict__ out)
{
    __shared__ float hr[8][260];
    int m0 = blockIdx.x << 3;
    int t = threadIdx.x;
    {
        int r = t >> 5, c = (t & 31) << 3;
        uint4 raw = *(const uint4*)(h + (size_t)(m0 + r) * 256 + c);
        const uint16_t* us = (const uint16_t*)&raw;
#pragma unroll
        for (int j = 0; j < 8; ++j) hr[r][c + j] = bf2f(us[j]);
    }
    __syncthreads();
    int r = t >> 5, n = t & 31;
    float acc = b2[n];
#pragma unroll 4
    for (int k = 0; k < 256; ++k) acc += hr[r][k] * w2[(size_t)k * 32 + n];
    out[(size_t)(m0 + r) * 32 + n] = acc;
}

// ---------------- host ----------------
extern "C" void kernel_launch(void* const* d_in, const int* in_sizes, int n_in,
                              void* d_out, int out_size, void* d_ws, size_t ws_size,
                              hipStream_t stream)
{
    const float* action = (const float*)d_in[0];
    const float* obs    = (const float*)d_in[1];
    const float* w_enc  = (const float*)d_in[2];
    const float* ln0    = (const float*)d_in[3];
    const float* wq1 = (const float*)d_in[4];
    const float* wk1 = (const float*)d_in[5];
    const float* wv1 = (const float*)d_in[6];
    const float* wg1 = (const float*)d_in[7];
    const float* wo1 = (const float*)d_in[8];
    const float* gns1 = (const float*)d_in[9];
    const float* gnb1 = (const float*)d_in[10];
    const float* ln1  = (const float*)d_in[11];
    const float* wq2 = (const float*)d_in[12];
    const float* wk2 = (const float*)d_in[13];
    const float* wv2 = (const float*)d_in[14];
    const float* wg2 = (const float*)d_in[15];
    const float* wo2 = (const float*)d_in[16];
    const float* gns2 = (const float*)d_in[17];
    const float* gnb2 = (const float*)d_in[18];
    const float* ln2  = (const float*)d_in[19];
    const float* swgp = (const float*)d_in[20];
    const float* sw1p = (const float*)d_in[21];
    const float* sw2p = (const float*)d_in[22];
    const float* ln3  = (const float*)d_in[23];
    const float* hw1  = (const float*)d_in[24];
    const float* hb1  = (const float*)d_in[25];
    const float* hln  = (const float*)d_in[26];
    const float* hw2  = (const float*)d_in[27];
    const float* hb2  = (const float*)d_in[28];
    float* outp = (float*)d_out;

    char* ws = (char*)d_ws;
    uint16_t* wt   = (uint16_t*)(ws + 0);          // 10,518,528 B bf16 transposed weights
    uint16_t* actb = (uint16_t*)(ws + 10518528);
    uint16_t* obsb = (uint16_t*)(ws + 11567104);
    float*    xf   = (float*)   (ws + 19955712);
    uint16_t* xb   = (uint16_t*)(ws + 36732928);
    uint16_t* bq   = (uint16_t*)(ws + 45121536);
    uint16_t* bk   = (uint16_t*)(ws + 53510144);
    uint16_t* bv   = (uint16_t*)(ws + 61898752);
    uint16_t* bg   = (uint16_t*)(ws + 70287360);
    uint16_t* brg  = (uint16_t*)(ws + 78675968);   // end 87,064,576

    uint16_t* wtenc = wt;
    uint16_t* hw1t  = wt + 2564096;
    auto WTp = [&](int ti, int s) { return wt + 8192 + (size_t)(ti * 3 + s) * 65536; };

    GArg ga;
    {
        const double a = log(1.0 / 32.0), bb = log(1.0 / 512.0);
        for (int hh = 0; hh < 8; ++hh) {
            double lg = a + (bb - a) * hh / 7.0;
            double gam = 1.0 - exp(lg);
            ga.l2g[hh] = (float)(log(gam) / log(2.0));
        }
    }
    TArg ta;
    ta.src[0] = w_enc;
    ta.src[1] = wq1;  ta.src[2] = wk1;  ta.src[3] = wv1;  ta.src[4] = wg1;  ta.src[5] = wo1;
    ta.src[6] = wq2;  ta.src[7] = wk2;  ta.src[8] = wv2;  ta.src[9] = wg2;  ta.src[10] = wo2;
    ta.src[11] = swgp; ta.src[12] = sw1p; ta.src[13] = sw2p; ta.src[14] = hw1;

    tpose_k<<<dim3(4, 8, 41), 256, 0, stream>>>(ta, wt);
    cvt_k<<<512, 256, 0, stream>>>(action, actb, 131072);
    cvt_k<<<4096, 256, 0, stream>>>(obs, obsb, 1048576);

    dim3 GB(512), TB(256);
    // encoder: x = rmsnorm(gelu(action @ w_enc), ln0)
    gemm_k<EP_GELU_RMS><<<GB, TB, 0, stream>>>(actb, wtenc, 32, nullptr, nullptr, nullptr, ln0, xf, xb);

    for (int b3 = 0; b3 < 3; ++b3) {
        // retention 1 (self)
        gemm_k<EP_NONE><<<GB, TB, 0, stream>>>(xb, WTp(0, b3), 256, nullptr, nullptr, nullptr, nullptr, nullptr, bq);
        gemm_k<EP_NONE><<<GB, TB, 0, stream>>>(xb, WTp(1, b3), 256, nullptr, nullptr, nullptr, nullptr, nullptr, bk);
        gemm_k<EP_NONE><<<GB, TB, 0, stream>>>(xb, WTp(2, b3), 256, nullptr, nullptr, nullptr, nullptr, nullptr, bv);
        gemm_k<EP_NONE><<<GB, TB, 0, stream>>>(xb, WTp(3, b3), 256, nullptr, nullptr, nullptr, nullptr, nullptr, bg);
        attn_k<<<512, 256, 0, stream>>>(bq, bk, bv, bg, gns1 + b3 * 256, gnb1 + b3 * 256, brg, ga);
        gemm_k<EP_RESID_RMS><<<GB, TB, 0, stream>>>(brg, WTp(4, b3), 256, nullptr, xf, nullptr, ln1 + b3 * 256, xf, xb);
        // retention 2 (cross: q,gate from obs_rep; k,v from x; resid obs_rep)
        gemm_k<EP_NONE><<<GB, TB, 0, stream>>>(obsb, WTp(5, b3), 256, nullptr, nullptr, nullptr, nullptr, nullptr, bq);
        gemm_k<EP_NONE><<<GB, TB, 0, stream>>>(xb,   WTp(6, b3), 256, nullptr, nullptr, nullptr, nullptr, nullptr, bk);
        gemm_k<EP_NONE><<<GB, TB, 0, stream>>>(xb,   WTp(7, b3), 256, nullptr, nullptr, nullptr, nullptr, nullptr, bv);
        gemm_k<EP_NONE><<<GB, TB, 0, stream>>>(obsb, WTp(8, b3), 256, nullptr, nullptr, nullptr, nullptr, nullptr, bg);
        attn_k<<<512, 256, 0, stream>>>(bq, bk, bv, bg, gns2 + b3 * 256, gnb2 + b3 * 256, brg, ga);
        gemm_k<EP_RESID_RMS><<<GB, TB, 0, stream>>>(brg, WTp(9, b3), 256, nullptr, obs, nullptr, ln2 + b3 * 256, xf, xb);
        // swiglu mlp
        gemm_k<EP_NONE><<<GB, TB, 0, stream>>>(xb, WTp(10, b3), 256, nullptr, nullptr, nullptr, nullptr, nullptr, bq);
        gemm_k<EP_MUL><<<GB, TB, 0, stream>>>(xb, WTp(11, b3), 256, nullptr, nullptr, bq, nullptr, nullptr, bk);
        gemm_k<EP_RESID_RMS><<<GB, TB, 0, stream>>>(bk, WTp(12, b3), 256, nullptr, xf, nullptr, ln3 + b3 * 256, xf, xb);
    }
    // head
    gemm_k<EP_GELU_RMS><<<GB, TB, 0, stream>>>(xb, hw1t, 256, hb1, nullptr, nullptr, hln, nullptr, bq);
    head_out_k<<<2048, 256, 0, stream>>>(bq, hw2, hb2, outp);
}

// Round 2
// 713.320 us; speedup vs baseline: 1.2052x; 1.2052x over previous
//
#include <hip/hip_runtime.h>
#include <cstdint>
#include <cmath>

typedef __attribute__((ext_vector_type(8))) short short8;
typedef __attribute__((ext_vector_type(4))) float floatx4;

#define DEV static __device__ __forceinline__

DEV float bf2f(uint16_t u) {
    union { uint32_t i; float f; } v; v.i = ((uint32_t)u) << 16; return v.f;
}
DEV uint16_t f2bf(float f) {
    union { float f; uint32_t i; } v; v.f = f;
    uint32_t r = (v.i + 0x7FFFu + ((v.i >> 16) & 1u)) >> 16;
    return (uint16_t)r;
}
DEV float swishf(float x) { return x / (1.f + __expf(-x)); }
DEV float geluf(float x) {
    const float c = 0.7978845608028654f;
    float t = tanhf(c * (x + 0.044715f * x * x * x));
    return 0.5f * x * (1.f + t);
}

DEV void gl_lds16(const uint16_t* g, uint16_t* l) {
    __builtin_amdgcn_global_load_lds(
        (const __attribute__((address_space(1))) uint32_t*)g,
        (__attribute__((address_space(3))) uint32_t*)l, 16, 0, 0);
}

// ---------------- convert fp32 -> bf16 (flat) ----------------
__global__ __launch_bounds__(256) void cvt_k(const float* __restrict__ src,
                                             uint16_t* __restrict__ dst, int n4) {
    int i = blockIdx.x * 256 + threadIdx.x;
    if (i >= n4) return;
    float4 f = ((const float4*)src)[i];
    uint16_t tmp[4] = { f2bf(f.x), f2bf(f.y), f2bf(f.z), f2bf(f.w) };
    ((uint2*)dst)[i] = *(uint2*)tmp;
}

// ---- batched transpose+convert: W[K,N=256] -> packed chunks P[kc][n][32] bf16 ----
struct TArg { const float* src[15]; };

__global__ __launch_bounds__(256) void tpose_k(TArg ta, uint16_t* __restrict__ arena) {
    int z = blockIdx.z;
    const float* src; uint16_t* dst;
    if (z == 0) {
        if (blockIdx.y) return;
        src = ta.src[0]; dst = arena;                          // w_enc [32,256]
    } else if (z <= 39) {
        int q = z - 1; int ti = q / 3, s = q % 3;
        src = ta.src[1 + ti] + (size_t)s * 65536;
        dst = arena + 8192 + (size_t)(ti * 3 + s) * 65536;
    } else {
        src = ta.src[14]; dst = arena + 2564096;               // hw1
    }
    int k0 = blockIdx.y << 5;   // K chunk (32)
    int n0 = blockIdx.x << 6;   // N tile (64), N = 256
    __shared__ __align__(16) uint16_t tile[32][72];
    int t = threadIdx.x;
    {
        int r = t >> 3, c = (t & 7) << 3;
        const float* s0 = src + (size_t)(k0 + r) * 256 + n0 + c;
        float4 f0 = *(const float4*)s0;
        float4 f1 = *(const float4*)(s0 + 4);
        tile[r][c + 0] = f2bf(f0.x); tile[r][c + 1] = f2bf(f0.y);
        tile[r][c + 2] = f2bf(f0.z); tile[r][c + 3] = f2bf(f0.w);
        tile[r][c + 4] = f2bf(f1.x); tile[r][c + 5] = f2bf(f1.y);
        tile[r][c + 6] = f2bf(f1.z); tile[r][c + 7] = f2bf(f1.w);
    }
    __syncthreads();
    {
        int n = t >> 2, c = (t & 3) << 3;
        uint16_t tmp[8];
#pragma unroll
        for (int j = 0; j < 8; ++j) tmp[j] = tile[c + j][n];
        // packed: chunk (k0>>5), row (n0+n), k-offset c
        *(uint4*)&dst[(size_t)(k0 >> 5) * 8192 + (size_t)(n0 + n) * 32 + c] = *(uint4*)tmp;
    }
}

// -------- GEMM: A[M=16384,K] bf16 @ Wpacked (N=256), fused epilogues --------
enum { EP_NONE = 0, EP_GELU_RMS = 1, EP_RESID_RMS = 2, EP_MUL = 3 };

struct GemmArgs {
    const uint16_t* A[4];
    const uint16_t* W[4];
    uint16_t* O[4];
};

template<int EPI, int K>
__global__ __launch_bounds__(256, 2) void gemm2_k(
    GemmArgs ga,
    const float* __restrict__ bias, const float* __restrict__ resid,
    const uint16_t* __restrict__ mulg, const float* __restrict__ lnw,
    float* __restrict__ xout)
{
    __shared__ __align__(16) uint16_t Bs[2][2][8192];   // [buf][half][n*32+kk]
    __shared__ float rowsum[4][32];
    const int y = blockIdx.y;
    const uint16_t* __restrict__ A  = ga.A[y];
    const uint16_t* __restrict__ Wt = ga.W[y];
    uint16_t* __restrict__ O        = ga.O[y];
    const int t = threadIdx.x;
    const int w = t >> 6, lane = t & 63, l16 = lane & 15, lg = lane >> 4;
    const int m0 = blockIdx.x * 32;

    floatx4 acc[2][4];
#pragma unroll
    for (int i = 0; i < 2; ++i)
#pragma unroll
        for (int j = 0; j < 4; ++j) acc[i][j] = (floatx4){0.f, 0.f, 0.f, 0.f};

    const int nhalf = K >> 5;

    // stage one 32-K chunk (16 KB) via async global->LDS
    auto stage = [&](int c, uint16_t* ls) {
        const uint16_t* gp = Wt + (size_t)c * 8192;
#pragma unroll
        for (int j = 0; j < 4; ++j) {
            int off = w * 2048 + j * 512 + lane * 8;   // elements; 16 B per lane
            gl_lds16(gp + off, ls + off);
        }
    };
    // one 32-K compute sub-step
    auto compute = [&](const uint16_t* ls, int k0) {
        short8 aF[2], bF[4];
#pragma unroll
        for (int rt = 0; rt < 2; ++rt)
            aF[rt] = *(const short8*)(A + (size_t)(m0 + (rt << 4) + l16) * K + k0 + (lg << 3));
#pragma unroll
        for (int ct = 0; ct < 4; ++ct)
            bF[ct] = *(const short8*)&ls[((w << 6) + (ct << 4) + l16) * 32 + (lg << 3)];
#pragma unroll
        for (int rt = 0; rt < 2; ++rt)
#pragma unroll
            for (int ct = 0; ct < 4; ++ct)
                acc[rt][ct] = __builtin_amdgcn_mfma_f32_16x16x32_bf16(
                    aF[rt], bF[ct], acc[rt][ct], 0, 0, 0);
    };

    stage(0, Bs[0][0]);
    if (nhalf > 1) stage(1, Bs[0][1]);
    __syncthreads();
    int buf = 0;
#pragma unroll
    for (int c2 = 0; c2 < nhalf; c2 += 2) {
        if (c2 + 2 < nhalf) {
            stage(c2 + 2, Bs[buf ^ 1][0]);
            if (c2 + 3 < nhalf) stage(c2 + 3, Bs[buf ^ 1][1]);
        }
        compute(Bs[buf][0], c2 << 5);
        if (c2 + 1 < nhalf) compute(Bs[buf][1], (c2 + 1) << 5);
        __syncthreads();
        buf ^= 1;
    }

    // epilogue
    float v[2][4][4];
#pragma unroll
    for (int rt = 0; rt < 2; ++rt)
#pragma unroll
        for (int ct = 0; ct < 4; ++ct)
#pragma unroll
            for (int r = 0; r < 4; ++r) {
                int row = (rt << 4) + (lg << 2) + r;
                int col = (w << 6) + (ct << 4) + l16;
                size_t idx = (size_t)(m0 + row) * 256 + col;
                float x = acc[rt][ct][r];
                if (EPI == EP_GELU_RMS) { if (bias) x += bias[col]; x = geluf(x); }
                if (EPI == EP_RESID_RMS) x += resid[idx];
                if (EPI == EP_MUL) x *= swishf(bf2f(mulg[idx]));
                v[rt][ct][r] = x;
            }

    if (EPI == EP_GELU_RMS || EPI == EP_RESID_RMS) {
#pragma unroll
        for (int rt = 0; rt < 2; ++rt)
#pragma unroll
            for (int r = 0; r < 4; ++r) {
                float p = 0.f;
#pragma unroll
                for (int ct = 0; ct < 4; ++ct) p += v[rt][ct][r] * v[rt][ct][r];
                p += __shfl_xor(p, 1, 64); p += __shfl_xor(p, 2, 64);
                p += __shfl_xor(p, 4, 64); p += __shfl_xor(p, 8, 64);
                int row = (rt << 4) + (lg << 2) + r;
                if (l16 == 0) rowsum[w][row] = p;
            }
        __syncthreads();
#pragma unroll
        for (int rt = 0; rt < 2; ++rt)
#pragma unroll
            for (int r = 0; r < 4; ++r) {
                int row = (rt << 4) + (lg << 2) + r;
                float tot = rowsum[0][row] + rowsum[1][row] + rowsum[2][row] + rowsum[3][row];
                float rn = rsqrtf(tot * (1.f / 256.f) + 1e-6f);
#pragma unroll
                for (int ct = 0; ct < 4; ++ct) {
                    int col = (w << 6) + (ct << 4) + l16;
                    size_t idx = (size_t)(m0 + row) * 256 + col;
                    float o = v[rt][ct][r] * rn * lnw[col];
                    O[idx] = f2bf(o);
                    if (xout) xout[idx] = o;
                }
            }
    } else {
#pragma unroll
        for (int rt = 0; rt < 2; ++rt)
#pragma unroll
            for (int ct = 0; ct < 4; ++ct)
#pragma unroll
                for (int r = 0; r < 4; ++r) {
                    int row = (rt << 4) + (lg << 2) + r;
                    int col = (w << 6) + (ct << 4) + l16;
                    size_t idx = (size_t)(m0 + row) * 256 + col;
                    O[idx] = f2bf(v[rt][ct][r]);
                }
    }
}

// ---------------- retention attention, fused groupnorm + swish gate ----------------
struct GArg { float l2g[8]; };

__global__ __launch_bounds__(256) void attn_k(
    const uint16_t* __restrict__ q, const uint16_t* __restrict__ kbuf,
    const uint16_t* __restrict__ vbuf, const uint16_t* __restrict__ g,
    const float* __restrict__ gns, const float* __restrict__ gnb,
    uint16_t* __restrict__ out, GArg ga)
{
    __shared__ __align__(16) uint16_t QS[256][40];
    __shared__ __align__(16) uint16_t Ks[256][40];
    __shared__ __align__(16) uint16_t Vt[32][264];
    const int b = blockIdx.x >> 3, h = blockIdx.x & 7;
    const float l2g = ga.l2g[h];
    const int t = threadIdx.x, w = t >> 6, lane = t & 63, l16 = lane & 15, lg = lane >> 4;
    const size_t base = ((size_t)b * 256) * 256 + (size_t)h * 32;

    {
        const uint4* qr = (const uint4*)(q + base + (size_t)t * 256);
        *(uint4*)&QS[t][0] = qr[0]; *(uint4*)&QS[t][8] = qr[1];
        *(uint4*)&QS[t][16] = qr[2]; *(uint4*)&QS[t][24] = qr[3];
        const uint4* kr = (const uint4*)(kbuf + base + (size_t)t * 256);
        *(uint4*)&Ks[t][0] = kr[0]; *(uint4*)&Ks[t][8] = kr[1];
        *(uint4*)&Ks[t][16] = kr[2]; *(uint4*)&Ks[t][24] = kr[3];
        union { uint4 v4[4]; uint16_t u[32]; } vv;
        const uint4* vr = (const uint4*)(vbuf + base + (size_t)t * 256);
        vv.v4[0] = vr[0]; vv.v4[1] = vr[1]; vv.v4[2] = vr[2]; vv.v4[3] = vr[3];
#pragma unroll
        for (int d = 0; d < 32; ++d) Vt[d][t] = vv.u[d];
    }
    __syncthreads();

    short8 qF[4];
#pragma unroll
    for (int rt = 0; rt < 4; ++rt)
        qF[rt] = *(const short8*)&QS[(w << 6) + (rt << 4) + l16][lg << 3];
    __syncthreads();

    floatx4 racc[4][2];
#pragma unroll
    for (int i = 0; i < 4; ++i) { racc[i][0] = (floatx4){0,0,0,0}; racc[i][1] = (floatx4){0,0,0,0}; }

    const float invsq = 0.17677669529663687f;
    for (int jt = 0; jt < 8; ++jt) {
        const int j0 = jt << 5;
        floatx4 sacc[4][2];
#pragma unroll
        for (int i = 0; i < 4; ++i) { sacc[i][0] = (floatx4){0,0,0,0}; sacc[i][1] = (floatx4){0,0,0,0}; }
        short8 kF[2];
#pragma unroll
        for (int ct = 0; ct < 2; ++ct)
            kF[ct] = *(const short8*)&Ks[j0 + (ct << 4) + l16][lg << 3];
#pragma unroll
        for (int rt = 0; rt < 4; ++rt)
#pragma unroll
            for (int ct = 0; ct < 2; ++ct)
                sacc[rt][ct] = __builtin_amdgcn_mfma_f32_16x16x32_bf16(
                    qF[rt], kF[ct], sacc[rt][ct], 0, 0, 0);
#pragma unroll
        for (int rt = 0; rt < 4; ++rt)
#pragma unroll
            for (int ct = 0; ct < 2; ++ct)
#pragma unroll
                for (int r = 0; r < 4; ++r) {
                    int row = (rt << 4) + (lg << 2) + r;
                    int i = (w << 6) + row;
                    int j = j0 + (ct << 4) + l16;
                    float sv = 0.f;
                    if (i >= j)
                        sv = sacc[rt][ct][r] * invsq *
                             exp2f((float)((i >> 3) - (j >> 3)) * l2g);
                    QS[(w << 6) + row][(ct << 4) + l16] = f2bf(sv);
                }
        __syncthreads();
        short8 vF[2];
#pragma unroll
        for (int ct = 0; ct < 2; ++ct)
            vF[ct] = *(const short8*)&Vt[(ct << 4) + l16][j0 + (lg << 3)];
#pragma unroll
        for (int rt = 0; rt < 4; ++rt) {
            short8 sF = *(const short8*)&QS[(w << 6) + (rt << 4) + l16][lg << 3];
#pragma unroll
            for (int ct = 0; ct < 2; ++ct)
                racc[rt][ct] = __builtin_amdgcn_mfma_f32_16x16x32_bf16(
                    sF, vF[ct], racc[rt][ct], 0, 0, 0);
        }
        __syncthreads();
    }

#pragma unroll
    for (int rt = 0; rt < 4; ++rt)
#pragma unroll
        for (int r = 0; r < 4; ++r) {
            float v0 = racc[rt][0][r], v1 = racc[rt][1][r];
            float s1 = v0 + v1, s2 = v0 * v0 + v1 * v1;
            s1 += __shfl_xor(s1, 1, 64); s2 += __shfl_xor(s2, 1, 64);
            s1 += __shfl_xor(s1, 2, 64); s2 += __shfl_xor(s2, 2, 64);
            s1 += __shfl_xor(s1, 4, 64); s2 += __shfl_xor(s2, 4, 64);
            s1 += __shfl_xor(s1, 8, 64); s2 += __shfl_xor(s2, 8, 64);
            float mu = s1 * (1.f / 32.f);
            float var = s2 * (1.f / 32.f) - mu * mu;
            float rstd = rsqrtf(var + 1e-5f);
            int srow = (w << 6) + (rt << 4) + (lg << 2) + r;
            size_t obase = ((size_t)b * 256 + srow) * 256 + (size_t)h * 32;
#pragma unroll
            for (int ct = 0; ct < 2; ++ct) {
                int d = (ct << 4) + l16;
                float x = ct ? v1 : v0;
                float y = (x - mu) * rstd * gns[h * 32 + d] + gnb[h * 32 + d];
                float gv = swishf(bf2f(g[obase + d]));
                out[obase + d] = f2bf(y * gv);
            }
        }
}

// ---------------- final head: out = h @ hw2 + hb2 ----------------
__global__ __launch_bounds__(256) void head_out_k(
    const uint16_t* __restrict__ h, const float* __restrict__ w2,
    const float* __restrict__ b2, float* __restrict__ out)
{
    __shared__ float hr[8][260];
    int m0 = blockIdx.x << 3;
    int t = threadIdx.x;
    {
        int r = t >> 5, c = (t & 31) << 3;
        uint4 raw = *(const uint4*)(h + (size_t)(m0 + r) * 256 + c);
        const uint16_t* us = (const uint16_t*)&raw;
#pragma unroll
        for (int j = 0; j < 8; ++j) hr[r][c + j] = bf2f(us[j]);
    }
    __syncthreads();
    int r = t >> 5, n = t & 31;
    float acc = b2[n];
#pragma unroll 4
    for (int k = 0; k < 256; ++k) acc += hr[r][k] * w2[(size_t)k * 32 + n];
    out[(size_t)(m0 + r) * 32 + n] = acc;
}

// ---------------- host ----------------
extern "C" void kernel_launch(void* const* d_in, const int* in_sizes, int n_in,
                              void* d_out, int out_size, void* d_ws, size_t ws_size,
                              hipStream_t stream)
{
    const float* action = (const float*)d_in[0];
    const float* obs    = (const float*)d_in[1];
    const float* w_enc  = (const float*)d_in[2];
    const float* ln0    = (const float*)d_in[3];
    const float* wq1 = (const float*)d_in[4];
    const float* wk1 = (const float*)d_in[5];
    const float* wv1 = (const float*)d_in[6];
    const float* wg1 = (const float*)d_in[7];
    const float* wo1 = (const float*)d_in[8];
    const float* gns1 = (const float*)d_in[9];
    const float* gnb1 = (const float*)d_in[10];
    const float* ln1  = (const float*)d_in[11];
    const float* wq2 = (const float*)d_in[12];
    const float* wk2 = (const float*)d_in[13];
    const float* wv2 = (const float*)d_in[14];
    const float* wg2 = (const float*)d_in[15];
    const float* wo2 = (const float*)d_in[16];
    const float* gns2 = (const float*)d_in[17];
    const float* gnb2 = (const float*)d_in[18];
    const float* ln2  = (const float*)d_in[19];
    const float* swgp = (const float*)d_in[20];
    const float* sw1p = (const float*)d_in[21];
    const float* sw2p = (const float*)d_in[22];
    const float* ln3  = (const float*)d_in[23];
    const float* hw1  = (const float*)d_in[24];
    const float* hb1  = (const float*)d_in[25];
    const float* hln  = (const float*)d_in[26];
    const float* hw2  = (const float*)d_in[27];
    const float* hb2  = (const float*)d_in[28];
    float* outp = (float*)d_out;

    char* ws = (char*)d_ws;
    uint16_t* wt   = (uint16_t*)(ws + 0);
    uint16_t* actb = (uint16_t*)(ws + 10518528);
    uint16_t* obsb = (uint16_t*)(ws + 11567104);
    float*    xf   = (float*)   (ws + 19955712);
    uint16_t* xb   = (uint16_t*)(ws + 36732928);
    uint16_t* bq   = (uint16_t*)(ws + 45121536);
    uint16_t* bk   = (uint16_t*)(ws + 53510144);
    uint16_t* bv   = (uint16_t*)(ws + 61898752);
    uint16_t* bg   = (uint16_t*)(ws + 70287360);
    uint16_t* brg  = (uint16_t*)(ws + 78675968);

    uint16_t* wtenc = wt;
    uint16_t* hw1t  = wt + 2564096;
    auto WTp = [&](int ti, int s) { return wt + 8192 + (size_t)(ti * 3 + s) * 65536; };

    GArg gaD;
    {
        const double a = log(1.0 / 32.0), bb = log(1.0 / 512.0);
        for (int hh = 0; hh < 8; ++hh) {
            double lg = a + (bb - a) * hh / 7.0;
            double gam = 1.0 - exp(lg);
            gaD.l2g[hh] = (float)(log(gam) / log(2.0));
        }
    }
    TArg ta;
    ta.src[0] = w_enc;
    ta.src[1] = wq1;  ta.src[2] = wk1;  ta.src[3] = wv1;  ta.src[4] = wg1;  ta.src[5] = wo1;
    ta.src[6] = wq2;  ta.src[7] = wk2;  ta.src[8] = wv2;  ta.src[9] = wg2;  ta.src[10] = wo2;
    ta.src[11] = swgp; ta.src[12] = sw1p; ta.src[13] = sw2p; ta.src[14] = hw1;

    tpose_k<<<dim3(4, 8, 41), 256, 0, stream>>>(ta, wt);
    cvt_k<<<512, 256, 0, stream>>>(action, actb, 131072);
    cvt_k<<<4096, 256, 0, stream>>>(obs, obsb, 1048576);

    dim3 TB(256);
    auto g1 = [&](const uint16_t* A, const uint16_t* W, uint16_t* O) {
        GemmArgs g; g.A[0] = A; g.W[0] = W; g.O[0] = O;
        g.A[1] = g.A[2] = g.A[3] = A; g.W[1] = g.W[2] = g.W[3] = W;
        g.O[1] = g.O[2] = g.O[3] = O;
        return g;
    };

    // encoder: x = rmsnorm(gelu(action @ w_enc), ln0)
    gemm2_k<EP_GELU_RMS, 32><<<dim3(512, 1), TB, 0, stream>>>(
        g1(actb, wtenc, xb), nullptr, nullptr, nullptr, ln0, xf);

    for (int b3 = 0; b3 < 3; ++b3) {
        // retention 1 (self): fused q,k,v,g
        {
            GemmArgs g;
            g.A[0] = g.A[1] = g.A[2] = g.A[3] = xb;
            g.W[0] = WTp(0, b3); g.W[1] = WTp(1, b3); g.W[2] = WTp(2, b3); g.W[3] = WTp(3, b3);
            g.O[0] = bq; g.O[1] = bk; g.O[2] = bv; g.O[3] = bg;
            gemm2_k<EP_NONE, 256><<<dim3(512, 4), TB, 0, stream>>>(
                g, nullptr, nullptr, nullptr, nullptr, nullptr);
        }
        attn_k<<<512, TB, 0, stream>>>(bq, bk, bv, bg, gns1 + b3 * 256, gnb1 + b3 * 256, brg, gaD);
        gemm2_k<EP_RESID_RMS, 256><<<dim3(512, 1), TB, 0, stream>>>(
            g1(brg, WTp(4, b3), xb), nullptr, xf, nullptr, ln1 + b3 * 256, xf);
        // retention 2 (cross): q,g from obs_rep; k,v from x
        {
            GemmArgs g;
            g.A[0] = obsb; g.A[1] = xb; g.A[2] = xb; g.A[3] = obsb;
            g.W[0] = WTp(5, b3); g.W[1] = WTp(6, b3); g.W[2] = WTp(7, b3); g.W[3] = WTp(8, b3);
            g.O[0] = bq; g.O[1] = bk; g.O[2] = bv; g.O[3] = bg;
            gemm2_k<EP_NONE, 256><<<dim3(512, 4), TB, 0, stream>>>(
                g, nullptr, nullptr, nullptr, nullptr, nullptr);
        }
        attn_k<<<512, TB, 0, stream>>>(bq, bk, bv, bg, gns2 + b3 * 256, gnb2 + b3 * 256, brg, gaD);
        gemm2_k<EP_RESID_RMS, 256><<<dim3(512, 1), TB, 0, stream>>>(
            g1(brg, WTp(9, b3), xb), nullptr, obs, nullptr, ln2 + b3 * 256, xf);
        // swiglu mlp
        gemm2_k<EP_NONE, 256><<<dim3(512, 1), TB, 0, stream>>>(
            g1(xb, WTp(10, b3), bq), nullptr, nullptr, nullptr, nullptr, nullptr);
        gemm2_k<EP_MUL, 256><<<dim3(512, 1), TB, 0, stream>>>(
            g1(xb, WTp(11, b3), bk), nullptr, nullptr, bq, nullptr, nullptr);
        gemm2_k<EP_RESID_RMS, 256><<<dim3(512, 1), TB, 0, stream>>>(
            g1(bk, WTp(12, b3), xb), nullptr, xf, nullptr, ln3 + b3 * 256, xf);
    }
    // head
    gemm2_k<EP_GELU_RMS, 256><<<dim3(512, 1), TB, 0, stream>>>(
        g1(xb, hw1t, bq), hb1, nullptr, nullptr, hln, nullptr);
    head_out_k<<<2048, TB, 0, stream>>>(bq, hw2, hb2, outp);
}